// Round 17
// baseline (90.377 us; speedup 1.0000x reference)
//
#include <hip/hip_runtime.h>

#define S_LEN 4096   // H*W
#define C_CH  256
#define D_CH  128
// softmax scale for exp2: lambda = (1/sqrt(256)) * log2(e)  [applied at exp2, NOT folded
// into Q: fp8 e4m3 min-normal is 2^-6, lambda*q ~0.014 would hit denormals]
#define LAMBDA 0.09016844005555896f

typedef __attribute__((ext_vector_type(8)))  short short8;   // 8 x bf16 (4 VGPR)
typedef __attribute__((ext_vector_type(4)))  float f32x4;
typedef __attribute__((ext_vector_type(16))) float f32x16;

union PFrag { unsigned u[4]; short8 v; };

static __device__ __forceinline__ unsigned short f2bf(float x) {
    union { float f; unsigned u; } v; v.f = x;
    unsigned r = v.u + 0x7FFFu + ((v.u >> 16) & 1u);   // RNE
    return (unsigned short)(r >> 16);
}
static __device__ __forceinline__ float bf2f(unsigned short b) {
    union { unsigned u; float f; } v; v.u = ((unsigned)b) << 16; return v.f;
}

static __device__ __forceinline__ void gload_lds16(const void* g, void* l) {
    __builtin_amdgcn_global_load_lds(
        (const __attribute__((address_space(1))) void*)g,
        (__attribute__((address_space(3))) void*)l, 16, 0, 0);
}

// ---------- kernel 2: theta_w/phi_w f32 -> bf16, wb = [2][128][256] ----------
__global__ void nlm_wconv_kernel(const float* __restrict__ tw, const float* __restrict__ pw,
                                 unsigned short* __restrict__ wb) {
    int base = (blockIdx.x * 256 + threadIdx.x) * 4;
    const float* src = (base < 32768) ? (tw + base) : (pw + base - 32768);
    float4 v = *reinterpret_cast<const float4*>(src);
    ushort4 b; b.x = f2bf(v.x); b.y = f2bf(v.y); b.z = f2bf(v.z); b.w = f2bf(v.w);
    *reinterpret_cast<ushort4*>(wb + base) = b;
}

// ---------- kernel 3: projections Q/K (fp8 e4m3) + FUSED x->xb bf16 side-output ----
// Each wave's A-fragment loop touches x[c][s] for its 16 s x all 256 c exactly once,
// so xb ([n][c][s] bf16, the attention V operand) is emitted here for free (reads),
// replacing the former standalone conv kernel (saves a full 67 MB re-read of x).
__launch_bounds__(256, 1)
__global__ void nlm_proj_kernel(const float* __restrict__ x,
                                const unsigned short* __restrict__ wb,
                                const float* __restrict__ tb, const float* __restrict__ pbias,
                                unsigned char* __restrict__ Qb8, unsigned char* __restrict__ Kb8,
                                unsigned short* __restrict__ xb) {
    const int n    = blockIdx.y;
    const int wave = threadIdx.x >> 6;
    const int lane = threadIdx.x & 63;
    const int sl   = lane & 15, g = lane >> 4;
    const int s0   = blockIdx.x * 64 + wave * 16;
    const float* xn = x + (size_t)n * C_CH * S_LEN;
    unsigned short* xbn = xb + (size_t)n * C_CH * S_LEN;

    f32x4 acc[16];
    #pragma unroll
    for (int i = 0; i < 16; ++i) acc[i] = (f32x4){0.f, 0.f, 0.f, 0.f};

    #pragma unroll 1
    for (int cc = 0; cc < 8; ++cc) {
        short8 af;                                   // A[m=s][k=c]: lane m=sl, k=g*8+j
        #pragma unroll
        for (int j = 0; j < 8; ++j) {
            float v = xn[(size_t)(cc * 32 + g * 8 + j) * S_LEN + s0 + sl];
            af[j] = (short)f2bf(v);
        }
        #pragma unroll
        for (int j = 0; j < 8; ++j) {                // fused conv: xb[c][s] = bf16(x)
            xbn[(size_t)(cc * 32 + g * 8 + j) * S_LEN + s0 + sl] = (unsigned short)af[j];
        }
        #pragma unroll
        for (int t = 0; t < 16; ++t) {               // 0..7 theta tiles, 8..15 phi tiles
            const unsigned short* wp = wb + (size_t)(t >> 3) * (D_CH * C_CH)
                                          + (size_t)((t & 7) * 16 + sl) * C_CH + cc * 32 + g * 8;
            short8 bf = *reinterpret_cast<const short8*>(wp);
            acc[t] = __builtin_amdgcn_mfma_f32_16x16x32_bf16(af, bf, acc[t], 0, 0, 0);
        }
    }
    #pragma unroll
    for (int t = 0; t < 16; ++t) {
        const float bias = (t < 8 ? tb : pbias)[(t & 7) * 16 + sl];
        unsigned char* dst = (t < 8 ? Qb8 : Kb8) + (size_t)n * S_LEN * D_CH;
        const int col = (t & 7) * 16 + sl;
        float v0 = acc[t][0] + bias, v1 = acc[t][1] + bias;
        float v2 = acc[t][2] + bias, v3 = acc[t][3] + bias;
        unsigned u01, u23;                           // 2 fp8 in low 16 bits each (RNE, sat)
        asm("v_cvt_pk_fp8_f32 %0, %1, %2" : "=v"(u01) : "v"(v0), "v"(v1));
        asm("v_cvt_pk_fp8_f32 %0, %1, %2" : "=v"(u23) : "v"(v2), "v"(v3));
        dst[(size_t)(s0 + g * 4 + 0) * D_CH + col] = (unsigned char)(u01 & 0xff);
        dst[(size_t)(s0 + g * 4 + 1) * D_CH + col] = (unsigned char)((u01 >> 8) & 0xff);
        dst[(size_t)(s0 + g * 4 + 2) * D_CH + col] = (unsigned char)(u23 & 0xff);
        dst[(size_t)(s0 + g * 4 + 3) * D_CH + col] = (unsigned char)((u23 >> 8) & 0xff);
    }
}

// ---------- kernel 4: flash attention, 8-wave, BT=64, fp8 QK, t-split ----------
// r16 structure (verified best): swizzle g(row)=(row^(row>>3))&7 (conflict-free for
// 128B rows), bf16 partials, counted-vmcnt double-buffer, setprio MFMA clusters.
template<int TSPLIT>
__launch_bounds__(512, 2)
__global__ void nlm_attn_kernel(const unsigned char* __restrict__ Qb8,
                                const unsigned char* __restrict__ Kb8,
                                const unsigned short* __restrict__ xb,
                                unsigned short* __restrict__ part0,
                                unsigned short* __restrict__ part1,
                                unsigned short* __restrict__ part2,
                                unsigned short* __restrict__ part3,
                                float* __restrict__ lbuf) {
    constexpr int TRANGE = S_LEN / TSPLIT;
    constexpr int NITv   = TRANGE / 64;
    constexpr int TOTAL  = 64 * TSPLIT;
    // XCD swizzle: TOTAL/8 consecutive newb per XCD (r14 scheme).
    const int sid  = blockIdx.x;
    const int newb = (sid & 7) * (TOTAL / 8) + (sid >> 3);
    const int n    = newb / (16 * TSPLIT);
    const int th   = (newb >> 4) & (TSPLIT - 1);
    const int sb   = newb & 15;
    const int lane = threadIdx.x & 63;
    const int wave = threadIdx.x >> 6;               // 0..7
    const int l31  = lane & 31;
    const int h    = lane >> 5;
    const int s0   = sb * 256 + wave * 32;           // this wave's 32 q-rows
    const int tbase = th * TRANGE;

    __shared__ unsigned char  Klds[2][64 * 128];     // fp8 [t-local][d], g()-XOR swizzled
    __shared__ unsigned short Vlds[2][256 * 64];     // bf16 [c][t-local], g()-XOR swizzled

    const unsigned char* Qn8 = Qb8 + (size_t)n * S_LEN * D_CH;
    const unsigned char* Kn8 = Kb8 + (size_t)n * S_LEN * D_CH;
    const unsigned short* xn = xb + (size_t)n * C_CH * S_LEN;

    // Q fragments (B operand, fp8): lane (s=l31, h): d-bytes = ks*16 + h*8 + j
    long qf8[8];
    #pragma unroll
    for (int ks = 0; ks < 8; ++ks)
        qf8[ks] = *reinterpret_cast<const long*>(Qn8 + (size_t)(s0 + l31) * D_CH + ks * 16 + h * 8);

    f32x16 oacc[8];                                  // O^T: c-block cb*32.., s = s0+l31
    #pragma unroll
    for (int i = 0; i < 8; ++i)
        #pragma unroll
        for (int r = 0; r < 16; ++r) oacc[i][r] = 0.f;
    float lsum = 0.f;                                // per-lane partial row sum

    auto kstage = [&](int itv, int slot) {           // 64 rows x 128B fp8, 1 inst/wave
        const int it = itv < NITv ? itv : NITv - 1;  // clamp: tail stages dup tile (unread)
        const int t0 = tbase + it * 64;
        const int rl = wave * 8 + (lane >> 3);
        const int ch = (lane & 7) ^ ((rl ^ (rl >> 3)) & 7);   // LDS[r][q]=G[t0+r][q^g(r)]
        gload_lds16(Kn8 + (size_t)(t0 + rl) * D_CH + ch * 16,
                    &Klds[slot][wave * 8 * 128]);
    };
    auto vstage = [&](int itv, int slot) {           // 256 rows x 128B bf16, 4 insts/wave
        const int it = itv < NITv ? itv : NITv - 1;
        const int t0 = tbase + it * 64;
        #pragma unroll
        for (int i = 0; i < 4; ++i) {
            const int row = wave * 32 + i * 8 + (lane >> 3);
            const int ch = (lane & 7) ^ ((row ^ (row >> 3)) & 7);
            gload_lds16(xn + (size_t)row * S_LEN + t0 + ch * 8,
                        &Vlds[slot][(wave * 32 + i * 8) * 64]);
        }
    };

    // prologue: K(0), V(0)
    kstage(0, 0); vstage(0, 0);
    asm volatile("s_waitcnt vmcnt(0)" ::: "memory");

    const int flo = (l31 ^ (l31 >> 3)) & 7;          // g(l31); K hi-rows: g(32+l31)=flo^4
    const int fhi = flo ^ 4;

    #pragma unroll 1
    for (int it = 0; it < NITv; ++it) {
        const int cur = it & 1;
        __builtin_amdgcn_s_barrier();                // K(it),V(it) landed; buf cur^1 free
        __builtin_amdgcn_sched_barrier(0);
        kstage(it + 1, cur ^ 1);
        vstage(it + 1, cur ^ 1);

        // ---- QK(it): S^T = K_tile(64t x 128d) * Q^T(128d x 32s), fp8, 2 chains ----
        f32x16 sa, sb2;                              // t 0..31 / t 32..63
        #pragma unroll
        for (int r = 0; r < 16; ++r) { sa[r] = 0.f; sb2[r] = 0.f; }
        __builtin_amdgcn_s_setprio(1);
        #pragma unroll
        for (int ks = 0; ks < 8; ++ks) {             // A: lane (t,h): d-bytes=ks*16+h*8+j
            const int clo = ((ks ^ flo) * 16) + h * 8;
            const int chi = ((ks ^ fhi) * 16) + h * 8;
            long kflo = *reinterpret_cast<const long*>(&Klds[cur][l31 * 128 + clo]);
            long kfhi = *reinterpret_cast<const long*>(&Klds[cur][(32 + l31) * 128 + chi]);
            sa  = __builtin_amdgcn_mfma_f32_32x32x16_fp8_fp8(kflo, qf8[ks], sa,  0, 0, 0);
            sb2 = __builtin_amdgcn_mfma_f32_32x32x16_fp8_fp8(kfhi, qf8[ks], sb2, 0, 0, 0);
        }
        __builtin_amdgcn_s_setprio(0);

        // ---- exp(S*lambda) (no max) + P-frags (cvt_pk + permlane32_swap) ----
        PFrag pa0, pa1, pa2, pa3;
        float rs = 0.f;
        {
            float p[16];
            #pragma unroll
            for (int r = 0; r < 16; ++r) { p[r] = __builtin_amdgcn_exp2f(sa[r] * LAMBDA); rs += p[r]; }
            unsigned W0, W1, W2, W3, W4, W5, W6, W7;
            asm("v_cvt_pk_bf16_f32 %0, %1, %2" : "=v"(W0) : "v"(p[0]),  "v"(p[1]));
            asm("v_cvt_pk_bf16_f32 %0, %1, %2" : "=v"(W1) : "v"(p[2]),  "v"(p[3]));
            asm("v_cvt_pk_bf16_f32 %0, %1, %2" : "=v"(W2) : "v"(p[4]),  "v"(p[5]));
            asm("v_cvt_pk_bf16_f32 %0, %1, %2" : "=v"(W3) : "v"(p[6]),  "v"(p[7]));
            asm("v_cvt_pk_bf16_f32 %0, %1, %2" : "=v"(W4) : "v"(p[8]),  "v"(p[9]));
            asm("v_cvt_pk_bf16_f32 %0, %1, %2" : "=v"(W5) : "v"(p[10]), "v"(p[11]));
            asm("v_cvt_pk_bf16_f32 %0, %1, %2" : "=v"(W6) : "v"(p[12]), "v"(p[13]));
            asm("v_cvt_pk_bf16_f32 %0, %1, %2" : "=v"(W7) : "v"(p[14]), "v"(p[15]));
            asm("v_permlane32_swap_b32 %0, %1" : "+v"(W0), "+v"(W2));
            asm("v_permlane32_swap_b32 %0, %1" : "+v"(W1), "+v"(W3));
            asm("v_permlane32_swap_b32 %0, %1" : "+v"(W4), "+v"(W6));
            asm("v_permlane32_swap_b32 %0, %1" : "+v"(W5), "+v"(W7));
            pa0.u[0] = W0; pa0.u[1] = W1; pa0.u[2] = W2; pa0.u[3] = W3;
            pa1.u[0] = W4; pa1.u[1] = W5; pa1.u[2] = W6; pa1.u[3] = W7;
        }
        {
            float p[16];
            #pragma unroll
            for (int r = 0; r < 16; ++r) { p[r] = __builtin_amdgcn_exp2f(sb2[r] * LAMBDA); rs += p[r]; }
            unsigned W0, W1, W2, W3, W4, W5, W6, W7;
            asm("v_cvt_pk_bf16_f32 %0, %1, %2" : "=v"(W0) : "v"(p[0]),  "v"(p[1]));
            asm("v_cvt_pk_bf16_f32 %0, %1, %2" : "=v"(W1) : "v"(p[2]),  "v"(p[3]));
            asm("v_cvt_pk_bf16_f32 %0, %1, %2" : "=v"(W2) : "v"(p[4]),  "v"(p[5]));
            asm("v_cvt_pk_bf16_f32 %0, %1, %2" : "=v"(W3) : "v"(p[6]),  "v"(p[7]));
            asm("v_cvt_pk_bf16_f32 %0, %1, %2" : "=v"(W4) : "v"(p[8]),  "v"(p[9]));
            asm("v_cvt_pk_bf16_f32 %0, %1, %2" : "=v"(W5) : "v"(p[10]), "v"(p[11]));
            asm("v_cvt_pk_bf16_f32 %0, %1, %2" : "=v"(W6) : "v"(p[12]), "v"(p[13]));
            asm("v_cvt_pk_bf16_f32 %0, %1, %2" : "=v"(W7) : "v"(p[14]), "v"(p[15]));
            asm("v_permlane32_swap_b32 %0, %1" : "+v"(W0), "+v"(W2));
            asm("v_permlane32_swap_b32 %0, %1" : "+v"(W1), "+v"(W3));
            asm("v_permlane32_swap_b32 %0, %1" : "+v"(W4), "+v"(W6));
            asm("v_permlane32_swap_b32 %0, %1" : "+v"(W5), "+v"(W7));
            pa2.u[0] = W0; pa2.u[1] = W1; pa2.u[2] = W2; pa2.u[3] = W3;
            pa3.u[0] = W4; pa3.u[1] = W5; pa3.u[2] = W6; pa3.u[3] = W7;
        }
        lsum += rs;

        // ---- PV(it): O^T[c][s] += V(32c x 16t) * P(16t x 32s), bf16, 8 cb x 4 ks ----
        __builtin_amdgcn_s_setprio(1);
        #pragma unroll
        for (int cb = 0; cb < 8; ++cb) {
            const int c = cb * 32 + l31;
            const unsigned short* Vr = &Vlds[cur][c * 64];
            const int fv = flo ^ ((cb & 1) << 2);    // g(c) = g(l31) ^ ((cb*4)&7)
            short8 vf0 = *reinterpret_cast<const short8*>(&Vr[((0 + h) ^ fv) * 8]);
            short8 vf1 = *reinterpret_cast<const short8*>(&Vr[((2 + h) ^ fv) * 8]);
            short8 vf2 = *reinterpret_cast<const short8*>(&Vr[((4 + h) ^ fv) * 8]);
            short8 vf3 = *reinterpret_cast<const short8*>(&Vr[((6 + h) ^ fv) * 8]);
            oacc[cb] = __builtin_amdgcn_mfma_f32_32x32x16_bf16(vf0, pa0.v, oacc[cb], 0, 0, 0);
            oacc[cb] = __builtin_amdgcn_mfma_f32_32x32x16_bf16(vf1, pa1.v, oacc[cb], 0, 0, 0);
            oacc[cb] = __builtin_amdgcn_mfma_f32_32x32x16_bf16(vf2, pa2.v, oacc[cb], 0, 0, 0);
            oacc[cb] = __builtin_amdgcn_mfma_f32_32x32x16_bf16(vf3, pa3.v, oacc[cb], 0, 0, 0);
        }
        __builtin_amdgcn_s_setprio(0);

        // drain this body's K(it+1)+V(it+1) DMAs -> next barrier guarantees them landed
        asm volatile("s_waitcnt vmcnt(0)" ::: "memory");
        __builtin_amdgcn_sched_barrier(0);
    }

    // ---- epilogue: reduce lsum across h, store bf16 partial O^T and f32 l ----
    float lt = lsum + __shfl_xor(lsum, 32);          // full row sum for this t-chunk
    unsigned short* dst = (th == 0) ? part0 : (th == 1) ? part1 : (th == 2) ? part2 : part3;
    if (lane < 32) lbuf[th * 16384 + n * 4096 + s0 + lane] = lt;
    unsigned short* on = dst + (size_t)n * C_CH * S_LEN;
    #pragma unroll
    for (int cb = 0; cb < 8; ++cb) {
        #pragma unroll
        for (int r = 0; r < 16; ++r) {
            const int c = cb * 32 + (r & 3) + 8 * (r >> 2) + 4 * h;
            on[(size_t)c * S_LEN + s0 + l31] = f2bf(oacc[cb][r]);
        }
    }
}

// ---------- kernel 5: combine t-chunks: out = sum(bf16 p_i) / sum(l_i) ----------
template<int TSPLIT>
__global__ void nlm_combine_kernel(float* __restrict__ out,
                                   const unsigned short* __restrict__ p0,
                                   const unsigned short* __restrict__ p1,
                                   const unsigned short* __restrict__ p2,
                                   const unsigned short* __restrict__ p3,
                                   const float* __restrict__ lbuf) {
    const size_t e0 = ((size_t)blockIdx.x * 256 + threadIdx.x) * 4;
    const int n = (int)(e0 >> 20);
    const int s = (int)(e0 & 4095);
    ushort4 a = *reinterpret_cast<const ushort4*>(p0 + e0);
    ushort4 b = *reinterpret_cast<const ushort4*>(p1 + e0);
    float4 l0 = *reinterpret_cast<const float4*>(lbuf + n * 4096 + s);
    float4 l1 = *reinterpret_cast<const float4*>(lbuf + 16384 + n * 4096 + s);
    float4 o, l;
    o.x = bf2f(a.x) + bf2f(b.x); o.y = bf2f(a.y) + bf2f(b.y);
    o.z = bf2f(a.z) + bf2f(b.z); o.w = bf2f(a.w) + bf2f(b.w);
    l.x = l0.x + l1.x; l.y = l0.y + l1.y; l.z = l0.z + l1.z; l.w = l0.w + l1.w;
    if (TSPLIT == 4) {
        ushort4 c = *reinterpret_cast<const ushort4*>(p2 + e0);
        ushort4 d = *reinterpret_cast<const ushort4*>(p3 + e0);
        float4 l2 = *reinterpret_cast<const float4*>(lbuf + 2 * 16384 + n * 4096 + s);
        float4 l3 = *reinterpret_cast<const float4*>(lbuf + 3 * 16384 + n * 4096 + s);
        o.x += bf2f(c.x) + bf2f(d.x); o.y += bf2f(c.y) + bf2f(d.y);
        o.z += bf2f(c.z) + bf2f(d.z); o.w += bf2f(c.w) + bf2f(d.w);
        l.x += l2.x + l3.x; l.y += l2.y + l3.y; l.z += l2.z + l3.z; l.w += l2.w + l3.w;
    }
    float4 r;
    r.x = o.x / l.x; r.y = o.y / l.y; r.z = o.z / l.z; r.w = o.w / l.w;
    *reinterpret_cast<float4*>(out + e0) = r;
}

extern "C" void kernel_launch(void* const* d_in, const int* in_sizes, int n_in,
                              void* d_out, int out_size, void* d_ws, size_t ws_size,
                              hipStream_t stream) {
    const float* x  = (const float*)d_in[0];
    const float* tw = (const float*)d_in[1];
    const float* tb = (const float*)d_in[2];
    const float* pw = (const float*)d_in[3];
    const float* pb = (const float*)d_in[4];
    float* out = (float*)d_out;

    char* ws = (char*)d_ws;
    unsigned short* xb  = (unsigned short*)(ws);              //  8,388,608 B
    unsigned char*  Qb8 = (unsigned char*)(ws + 8388608);     //  2,097,152 B (fp8)
    unsigned char*  Kb8 = (unsigned char*)(ws + 12582912);    //  2,097,152 B (fp8)
    unsigned short* wb  = (unsigned short*)(ws + 16777216);   //    131,072 B
    float*          lb  = (float*)(ws + 16908288);            //    262,144 B
    unsigned short* p0  = (unsigned short*)(ws + 17825792);   //  8,388,608 B (bf16 partial)
    unsigned short* p1  = (unsigned short*)(ws + 26214400);   //  8,388,608 B
    unsigned short* p2  = (unsigned short*)(ws + 34603008);   //  8,388,608 B
    unsigned short* p3  = (unsigned short*)(ws + 42991616);   //  8,388,608 B

    nlm_wconv_kernel<<<64, 256, 0, stream>>>(tw, pw, wb);
    nlm_proj_kernel<<<dim3(64, 4), 256, 0, stream>>>(x, wb, tb, pb, Qb8, Kb8, xb);
    if (ws_size >= (size_t)51380224) {               // 4-way t-split: 256 blocks, 8 waves
        nlm_attn_kernel<4><<<256, 512, 0, stream>>>(Qb8, Kb8, xb, p0, p1, p2, p3, lb);
        nlm_combine_kernel<4><<<4096, 256, 0, stream>>>(out, p0, p1, p2, p3, lb);
    } else {                                          // fallback: 2-way t-split
        nlm_attn_kernel<2><<<128, 512, 0, stream>>>(Qb8, Kb8, xb, p0, p1, p0, p0, lb);
        nlm_combine_kernel<2><<<4096, 256, 0, stream>>>(out, p0, p1, p0, p0, lb);
    }
}

// Round 18
// 88.248 us; speedup vs baseline: 1.0241x; 1.0241x over previous
//
#include <hip/hip_runtime.h>

#define S_LEN 4096   // H*W
#define C_CH  256
#define D_CH  128
// softmax scale for exp2: lambda = (1/sqrt(256)) * log2(e)  [applied at exp2, NOT folded
// into Q: fp8 e4m3 min-normal is 2^-6, lambda*q ~0.014 would hit denormals]
#define LAMBDA 0.09016844005555896f

typedef __attribute__((ext_vector_type(8)))  short short8;   // 8 x bf16 (4 VGPR)
typedef __attribute__((ext_vector_type(4)))  float f32x4;
typedef __attribute__((ext_vector_type(16))) float f32x16;

union PFrag { unsigned u[4]; short8 v; };

static __device__ __forceinline__ unsigned short f2bf(float x) {
    union { float f; unsigned u; } v; v.f = x;
    unsigned r = v.u + 0x7FFFu + ((v.u >> 16) & 1u);   // RNE
    return (unsigned short)(r >> 16);
}
static __device__ __forceinline__ float bf2f(unsigned short b) {
    union { unsigned u; float f; } v; v.u = ((unsigned)b) << 16; return v.f;
}

static __device__ __forceinline__ void gload_lds16(const void* g, void* l) {
    __builtin_amdgcn_global_load_lds(
        (const __attribute__((address_space(1))) void*)g,
        (__attribute__((address_space(3))) void*)l, 16, 0, 0);
}

// ---------- kernel 2: theta_w/phi_w f32 -> bf16, wb = [2][128][256] ----------
__global__ void nlm_wconv_kernel(const float* __restrict__ tw, const float* __restrict__ pw,
                                 unsigned short* __restrict__ wb) {
    int base = (blockIdx.x * 256 + threadIdx.x) * 4;
    const float* src = (base < 32768) ? (tw + base) : (pw + base - 32768);
    float4 v = *reinterpret_cast<const float4*>(src);
    ushort4 b; b.x = f2bf(v.x); b.y = f2bf(v.y); b.z = f2bf(v.z); b.w = f2bf(v.w);
    *reinterpret_cast<ushort4*>(wb + base) = b;
}

// ---------- kernel 3: projections Q/K (fp8 e4m3) + FUSED x->xb bf16 side-output ----
__launch_bounds__(256, 1)
__global__ void nlm_proj_kernel(const float* __restrict__ x,
                                const unsigned short* __restrict__ wb,
                                const float* __restrict__ tb, const float* __restrict__ pbias,
                                unsigned char* __restrict__ Qb8, unsigned char* __restrict__ Kb8,
                                unsigned short* __restrict__ xb) {
    const int n    = blockIdx.y;
    const int wave = threadIdx.x >> 6;
    const int lane = threadIdx.x & 63;
    const int sl   = lane & 15, g = lane >> 4;
    const int s0   = blockIdx.x * 64 + wave * 16;
    const float* xn = x + (size_t)n * C_CH * S_LEN;
    unsigned short* xbn = xb + (size_t)n * C_CH * S_LEN;

    f32x4 acc[16];
    #pragma unroll
    for (int i = 0; i < 16; ++i) acc[i] = (f32x4){0.f, 0.f, 0.f, 0.f};

    #pragma unroll 1
    for (int cc = 0; cc < 8; ++cc) {
        short8 af;                                   // A[m=s][k=c]: lane m=sl, k=g*8+j
        #pragma unroll
        for (int j = 0; j < 8; ++j) {
            float v = xn[(size_t)(cc * 32 + g * 8 + j) * S_LEN + s0 + sl];
            af[j] = (short)f2bf(v);
        }
        #pragma unroll
        for (int j = 0; j < 8; ++j) {                // fused conv: xb[c][s] = bf16(x)
            xbn[(size_t)(cc * 32 + g * 8 + j) * S_LEN + s0 + sl] = (unsigned short)af[j];
        }
        #pragma unroll
        for (int t = 0; t < 16; ++t) {               // 0..7 theta tiles, 8..15 phi tiles
            const unsigned short* wp = wb + (size_t)(t >> 3) * (D_CH * C_CH)
                                          + (size_t)((t & 7) * 16 + sl) * C_CH + cc * 32 + g * 8;
            short8 bf = *reinterpret_cast<const short8*>(wp);
            acc[t] = __builtin_amdgcn_mfma_f32_16x16x32_bf16(af, bf, acc[t], 0, 0, 0);
        }
    }
    #pragma unroll
    for (int t = 0; t < 16; ++t) {
        const float bias = (t < 8 ? tb : pbias)[(t & 7) * 16 + sl];
        unsigned char* dst = (t < 8 ? Qb8 : Kb8) + (size_t)n * S_LEN * D_CH;
        const int col = (t & 7) * 16 + sl;
        float v0 = acc[t][0] + bias, v1 = acc[t][1] + bias;
        float v2 = acc[t][2] + bias, v3 = acc[t][3] + bias;
        unsigned u01, u23;                           // 2 fp8 in low 16 bits each (RNE, sat)
        asm("v_cvt_pk_fp8_f32 %0, %1, %2" : "=v"(u01) : "v"(v0), "v"(v1));
        asm("v_cvt_pk_fp8_f32 %0, %1, %2" : "=v"(u23) : "v"(v2), "v"(v3));
        dst[(size_t)(s0 + g * 4 + 0) * D_CH + col] = (unsigned char)(u01 & 0xff);
        dst[(size_t)(s0 + g * 4 + 1) * D_CH + col] = (unsigned char)((u01 >> 8) & 0xff);
        dst[(size_t)(s0 + g * 4 + 2) * D_CH + col] = (unsigned char)(u23 & 0xff);
        dst[(size_t)(s0 + g * 4 + 3) * D_CH + col] = (unsigned char)((u23 >> 8) & 0xff);
    }
}

// ---------- kernel 4: flash attention, 8-wave, BT=64, fp8 QK, t-split ----------
// r16 structure + PHASE INTERLEAVE: body order is now QK-lo, QK-hi, exp(sa)->pa01,
// PV(ks0,ks1), exp(sb2)->pa23, PV(ks2,ks3) — each VALU block issues while the prior
// MFMA cluster completes (in-order issue, parallel pipes), so the matrix pipe no
// longer idles through the ~300cy softmax phase (both waves/SIMD are barrier-synced
// and in-phase, so cross-wave coverage can't do this for us).
template<int TSPLIT>
__launch_bounds__(512, 2)
__global__ void nlm_attn_kernel(const unsigned char* __restrict__ Qb8,
                                const unsigned char* __restrict__ Kb8,
                                const unsigned short* __restrict__ xb,
                                unsigned short* __restrict__ part0,
                                unsigned short* __restrict__ part1,
                                unsigned short* __restrict__ part2,
                                unsigned short* __restrict__ part3,
                                float* __restrict__ lbuf) {
    constexpr int TRANGE = S_LEN / TSPLIT;
    constexpr int NITv   = TRANGE / 64;
    constexpr int TOTAL  = 64 * TSPLIT;
    // XCD swizzle: TOTAL/8 consecutive newb per XCD (r14 scheme).
    const int sid  = blockIdx.x;
    const int newb = (sid & 7) * (TOTAL / 8) + (sid >> 3);
    const int n    = newb / (16 * TSPLIT);
    const int th   = (newb >> 4) & (TSPLIT - 1);
    const int sb   = newb & 15;
    const int lane = threadIdx.x & 63;
    const int wave = threadIdx.x >> 6;               // 0..7
    const int l31  = lane & 31;
    const int h    = lane >> 5;
    const int s0   = sb * 256 + wave * 32;           // this wave's 32 q-rows
    const int tbase = th * TRANGE;

    __shared__ unsigned char  Klds[2][64 * 128];     // fp8 [t-local][d], g()-XOR swizzled
    __shared__ unsigned short Vlds[2][256 * 64];     // bf16 [c][t-local], g()-XOR swizzled

    const unsigned char* Qn8 = Qb8 + (size_t)n * S_LEN * D_CH;
    const unsigned char* Kn8 = Kb8 + (size_t)n * S_LEN * D_CH;
    const unsigned short* xn = xb + (size_t)n * C_CH * S_LEN;

    // Q fragments (B operand, fp8): lane (s=l31, h): d-bytes = ks*16 + h*8 + j
    long qf8[8];
    #pragma unroll
    for (int ks = 0; ks < 8; ++ks)
        qf8[ks] = *reinterpret_cast<const long*>(Qn8 + (size_t)(s0 + l31) * D_CH + ks * 16 + h * 8);

    f32x16 oacc[8];                                  // O^T: c-block cb*32.., s = s0+l31
    #pragma unroll
    for (int i = 0; i < 8; ++i)
        #pragma unroll
        for (int r = 0; r < 16; ++r) oacc[i][r] = 0.f;
    float lsum = 0.f;                                // per-lane partial row sum

    auto kstage = [&](int itv, int slot) {           // 64 rows x 128B fp8, 1 inst/wave
        const int it = itv < NITv ? itv : NITv - 1;  // clamp: tail stages dup tile (unread)
        const int t0 = tbase + it * 64;
        const int rl = wave * 8 + (lane >> 3);
        const int ch = (lane & 7) ^ ((rl ^ (rl >> 3)) & 7);   // LDS[r][q]=G[t0+r][q^g(r)]
        gload_lds16(Kn8 + (size_t)(t0 + rl) * D_CH + ch * 16,
                    &Klds[slot][wave * 8 * 128]);
    };
    auto vstage = [&](int itv, int slot) {           // 256 rows x 128B bf16, 4 insts/wave
        const int it = itv < NITv ? itv : NITv - 1;
        const int t0 = tbase + it * 64;
        #pragma unroll
        for (int i = 0; i < 4; ++i) {
            const int row = wave * 32 + i * 8 + (lane >> 3);
            const int ch = (lane & 7) ^ ((row ^ (row >> 3)) & 7);
            gload_lds16(xn + (size_t)row * S_LEN + t0 + ch * 8,
                        &Vlds[slot][(wave * 32 + i * 8) * 64]);
        }
    };

    // prologue: K(0), V(0)
    kstage(0, 0); vstage(0, 0);
    asm volatile("s_waitcnt vmcnt(0)" ::: "memory");

    const int flo = (l31 ^ (l31 >> 3)) & 7;          // g(l31); K hi-rows: g(32+l31)=flo^4
    const int fhi = flo ^ 4;

    #pragma unroll 1
    for (int it = 0; it < NITv; ++it) {
        const int cur = it & 1;
        __builtin_amdgcn_s_barrier();                // K(it),V(it) landed; buf cur^1 free
        __builtin_amdgcn_sched_barrier(0);
        kstage(it + 1, cur ^ 1);
        vstage(it + 1, cur ^ 1);

        // ---- QK(it): S^T = K_tile(64t x 128d) * Q^T(128d x 32s), fp8, 2 chains ----
        f32x16 sa, sb2;                              // t 0..31 / t 32..63
        #pragma unroll
        for (int r = 0; r < 16; ++r) { sa[r] = 0.f; sb2[r] = 0.f; }
        __builtin_amdgcn_s_setprio(1);
        #pragma unroll
        for (int ks = 0; ks < 8; ++ks) {             // A: lane (t,h): d-bytes=ks*16+h*8+j
            const int clo = ((ks ^ flo) * 16) + h * 8;
            const int chi = ((ks ^ fhi) * 16) + h * 8;
            long kflo = *reinterpret_cast<const long*>(&Klds[cur][l31 * 128 + clo]);
            long kfhi = *reinterpret_cast<const long*>(&Klds[cur][(32 + l31) * 128 + chi]);
            sa  = __builtin_amdgcn_mfma_f32_32x32x16_fp8_fp8(kflo, qf8[ks], sa,  0, 0, 0);
            sb2 = __builtin_amdgcn_mfma_f32_32x32x16_fp8_fp8(kfhi, qf8[ks], sb2, 0, 0, 0);
        }
        __builtin_amdgcn_s_setprio(0);

        // ---- phase 1: exp(sa) -> pa0/pa1 (VALU; overlaps QK-hi MFMA completion) ----
        PFrag pa0, pa1, pa2, pa3;
        float rs = 0.f;
        {
            float p[16];
            #pragma unroll
            for (int r = 0; r < 16; ++r) { p[r] = __builtin_amdgcn_exp2f(sa[r] * LAMBDA); rs += p[r]; }
            unsigned W0, W1, W2, W3, W4, W5, W6, W7;
            asm("v_cvt_pk_bf16_f32 %0, %1, %2" : "=v"(W0) : "v"(p[0]),  "v"(p[1]));
            asm("v_cvt_pk_bf16_f32 %0, %1, %2" : "=v"(W1) : "v"(p[2]),  "v"(p[3]));
            asm("v_cvt_pk_bf16_f32 %0, %1, %2" : "=v"(W2) : "v"(p[4]),  "v"(p[5]));
            asm("v_cvt_pk_bf16_f32 %0, %1, %2" : "=v"(W3) : "v"(p[6]),  "v"(p[7]));
            asm("v_cvt_pk_bf16_f32 %0, %1, %2" : "=v"(W4) : "v"(p[8]),  "v"(p[9]));
            asm("v_cvt_pk_bf16_f32 %0, %1, %2" : "=v"(W5) : "v"(p[10]), "v"(p[11]));
            asm("v_cvt_pk_bf16_f32 %0, %1, %2" : "=v"(W6) : "v"(p[12]), "v"(p[13]));
            asm("v_cvt_pk_bf16_f32 %0, %1, %2" : "=v"(W7) : "v"(p[14]), "v"(p[15]));
            asm("v_permlane32_swap_b32 %0, %1" : "+v"(W0), "+v"(W2));
            asm("v_permlane32_swap_b32 %0, %1" : "+v"(W1), "+v"(W3));
            asm("v_permlane32_swap_b32 %0, %1" : "+v"(W4), "+v"(W6));
            asm("v_permlane32_swap_b32 %0, %1" : "+v"(W5), "+v"(W7));
            pa0.u[0] = W0; pa0.u[1] = W1; pa0.u[2] = W2; pa0.u[3] = W3;
            pa1.u[0] = W4; pa1.u[1] = W5; pa1.u[2] = W6; pa1.u[3] = W7;
        }

        // ---- phase 2: PV ks0/ks1 (16 MFMA; issues while nothing depends on sb2 yet) --
        __builtin_amdgcn_s_setprio(1);
        #pragma unroll
        for (int cb = 0; cb < 8; ++cb) {
            const int c = cb * 32 + l31;
            const unsigned short* Vr = &Vlds[cur][c * 64];
            const int fv = flo ^ ((cb & 1) << 2);    // g(c) = g(l31) ^ ((cb*4)&7)
            short8 vf0 = *reinterpret_cast<const short8*>(&Vr[((0 + h) ^ fv) * 8]);
            short8 vf1 = *reinterpret_cast<const short8*>(&Vr[((2 + h) ^ fv) * 8]);
            oacc[cb] = __builtin_amdgcn_mfma_f32_32x32x16_bf16(vf0, pa0.v, oacc[cb], 0, 0, 0);
            oacc[cb] = __builtin_amdgcn_mfma_f32_32x32x16_bf16(vf1, pa1.v, oacc[cb], 0, 0, 0);
        }
        __builtin_amdgcn_s_setprio(0);

        // ---- phase 3: exp(sb2) -> pa2/pa3 (VALU; overlaps PV ks0/ks1 MFMAs) ----
        {
            float p[16];
            #pragma unroll
            for (int r = 0; r < 16; ++r) { p[r] = __builtin_amdgcn_exp2f(sb2[r] * LAMBDA); rs += p[r]; }
            unsigned W0, W1, W2, W3, W4, W5, W6, W7;
            asm("v_cvt_pk_bf16_f32 %0, %1, %2" : "=v"(W0) : "v"(p[0]),  "v"(p[1]));
            asm("v_cvt_pk_bf16_f32 %0, %1, %2" : "=v"(W1) : "v"(p[2]),  "v"(p[3]));
            asm("v_cvt_pk_bf16_f32 %0, %1, %2" : "=v"(W2) : "v"(p[4]),  "v"(p[5]));
            asm("v_cvt_pk_bf16_f32 %0, %1, %2" : "=v"(W3) : "v"(p[6]),  "v"(p[7]));
            asm("v_cvt_pk_bf16_f32 %0, %1, %2" : "=v"(W4) : "v"(p[8]),  "v"(p[9]));
            asm("v_cvt_pk_bf16_f32 %0, %1, %2" : "=v"(W5) : "v"(p[10]), "v"(p[11]));
            asm("v_cvt_pk_bf16_f32 %0, %1, %2" : "=v"(W6) : "v"(p[12]), "v"(p[13]));
            asm("v_cvt_pk_bf16_f32 %0, %1, %2" : "=v"(W7) : "v"(p[14]), "v"(p[15]));
            asm("v_permlane32_swap_b32 %0, %1" : "+v"(W0), "+v"(W2));
            asm("v_permlane32_swap_b32 %0, %1" : "+v"(W1), "+v"(W3));
            asm("v_permlane32_swap_b32 %0, %1" : "+v"(W4), "+v"(W6));
            asm("v_permlane32_swap_b32 %0, %1" : "+v"(W5), "+v"(W7));
            pa2.u[0] = W0; pa2.u[1] = W1; pa2.u[2] = W2; pa2.u[3] = W3;
            pa3.u[0] = W4; pa3.u[1] = W5; pa3.u[2] = W6; pa3.u[3] = W7;
        }
        lsum += rs;

        // ---- phase 4: PV ks2/ks3 (16 MFMA) ----
        __builtin_amdgcn_s_setprio(1);
        #pragma unroll
        for (int cb = 0; cb < 8; ++cb) {
            const int c = cb * 32 + l31;
            const unsigned short* Vr = &Vlds[cur][c * 64];
            const int fv = flo ^ ((cb & 1) << 2);
            short8 vf2 = *reinterpret_cast<const short8*>(&Vr[((4 + h) ^ fv) * 8]);
            short8 vf3 = *reinterpret_cast<const short8*>(&Vr[((6 + h) ^ fv) * 8]);
            oacc[cb] = __builtin_amdgcn_mfma_f32_32x32x16_bf16(vf2, pa2.v, oacc[cb], 0, 0, 0);
            oacc[cb] = __builtin_amdgcn_mfma_f32_32x32x16_bf16(vf3, pa3.v, oacc[cb], 0, 0, 0);
        }
        __builtin_amdgcn_s_setprio(0);

        // drain this body's K(it+1)+V(it+1) DMAs -> next barrier guarantees them landed
        asm volatile("s_waitcnt vmcnt(0)" ::: "memory");
        __builtin_amdgcn_sched_barrier(0);
    }

    // ---- epilogue: reduce lsum across h, store bf16 partial O^T and f32 l ----
    float lt = lsum + __shfl_xor(lsum, 32);          // full row sum for this t-chunk
    unsigned short* dst = (th == 0) ? part0 : (th == 1) ? part1 : (th == 2) ? part2 : part3;
    if (lane < 32) lbuf[th * 16384 + n * 4096 + s0 + lane] = lt;
    unsigned short* on = dst + (size_t)n * C_CH * S_LEN;
    #pragma unroll
    for (int cb = 0; cb < 8; ++cb) {
        #pragma unroll
        for (int r = 0; r < 16; ++r) {
            const int c = cb * 32 + (r & 3) + 8 * (r >> 2) + 4 * h;
            on[(size_t)c * S_LEN + s0 + l31] = f2bf(oacc[cb][r]);
        }
    }
}

// ---------- kernel 5: combine t-chunks: out = sum(bf16 p_i) / sum(l_i) ----------
template<int TSPLIT>
__global__ void nlm_combine_kernel(float* __restrict__ out,
                                   const unsigned short* __restrict__ p0,
                                   const unsigned short* __restrict__ p1,
                                   const unsigned short* __restrict__ p2,
                                   const unsigned short* __restrict__ p3,
                                   const float* __restrict__ lbuf) {
    const size_t e0 = ((size_t)blockIdx.x * 256 + threadIdx.x) * 4;
    const int n = (int)(e0 >> 20);
    const int s = (int)(e0 & 4095);
    ushort4 a = *reinterpret_cast<const ushort4*>(p0 + e0);
    ushort4 b = *reinterpret_cast<const ushort4*>(p1 + e0);
    float4 l0 = *reinterpret_cast<const float4*>(lbuf + n * 4096 + s);
    float4 l1 = *reinterpret_cast<const float4*>(lbuf + 16384 + n * 4096 + s);
    float4 o, l;
    o.x = bf2f(a.x) + bf2f(b.x); o.y = bf2f(a.y) + bf2f(b.y);
    o.z = bf2f(a.z) + bf2f(b.z); o.w = bf2f(a.w) + bf2f(b.w);
    l.x = l0.x + l1.x; l.y = l0.y + l1.y; l.z = l0.z + l1.z; l.w = l0.w + l1.w;
    if (TSPLIT == 4) {
        ushort4 c = *reinterpret_cast<const ushort4*>(p2 + e0);
        ushort4 d = *reinterpret_cast<const ushort4*>(p3 + e0);
        float4 l2 = *reinterpret_cast<const float4*>(lbuf + 2 * 16384 + n * 4096 + s);
        float4 l3 = *reinterpret_cast<const float4*>(lbuf + 3 * 16384 + n * 4096 + s);
        o.x += bf2f(c.x) + bf2f(d.x); o.y += bf2f(c.y) + bf2f(d.y);
        o.z += bf2f(c.z) + bf2f(d.z); o.w += bf2f(c.w) + bf2f(d.w);
        l.x += l2.x + l3.x; l.y += l2.y + l3.y; l.z += l2.z + l3.z; l.w += l2.w + l3.w;
    }
    float4 r;
    r.x = o.x / l.x; r.y = o.y / l.y; r.z = o.z / l.z; r.w = o.w / l.w;
    *reinterpret_cast<float4*>(out + e0) = r;
}

extern "C" void kernel_launch(void* const* d_in, const int* in_sizes, int n_in,
                              void* d_out, int out_size, void* d_ws, size_t ws_size,
                              hipStream_t stream) {
    const float* x  = (const float*)d_in[0];
    const float* tw = (const float*)d_in[1];
    const float* tb = (const float*)d_in[2];
    const float* pw = (const float*)d_in[3];
    const float* pb = (const float*)d_in[4];
    float* out = (float*)d_out;

    char* ws = (char*)d_ws;
    unsigned short* xb  = (unsigned short*)(ws);              //  8,388,608 B
    unsigned char*  Qb8 = (unsigned char*)(ws + 8388608);     //  2,097,152 B (fp8)
    unsigned char*  Kb8 = (unsigned char*)(ws + 12582912);    //  2,097,152 B (fp8)
    unsigned short* wb  = (unsigned short*)(ws + 16777216);   //    131,072 B
    float*          lb  = (float*)(ws + 16908288);            //    262,144 B
    unsigned short* p0  = (unsigned short*)(ws + 17825792);   //  8,388,608 B (bf16 partial)
    unsigned short* p1  = (unsigned short*)(ws + 26214400);   //  8,388,608 B
    unsigned short* p2  = (unsigned short*)(ws + 34603008);   //  8,388,608 B
    unsigned short* p3  = (unsigned short*)(ws + 42991616);   //  8,388,608 B

    nlm_wconv_kernel<<<64, 256, 0, stream>>>(tw, pw, wb);
    nlm_proj_kernel<<<dim3(64, 4), 256, 0, stream>>>(x, wb, tb, pb, Qb8, Kb8, xb);
    if (ws_size >= (size_t)51380224) {               // 4-way t-split: 256 blocks, 8 waves
        nlm_attn_kernel<4><<<256, 512, 0, stream>>>(Qb8, Kb8, xb, p0, p1, p2, p3, lb);
        nlm_combine_kernel<4><<<4096, 256, 0, stream>>>(out, p0, p1, p2, p3, lb);
    } else {                                          // fallback: 2-way t-split
        nlm_attn_kernel<2><<<128, 512, 0, stream>>>(Qb8, Kb8, xb, p0, p1, p0, p0, lb);
        nlm_combine_kernel<2><<<4096, 256, 0, stream>>>(out, p0, p1, p0, p0, lb);
    }
}